// Round 1
// baseline (341.480 us; speedup 1.0000x reference)
//
#include <hip/hip_runtime.h>

#define QN 128
#define KN 16
#define TERMS (QN*KN)      // 2048
#define PPT 4
#define MBLK 256

#define G_CONST   0.004301
#define LOG2E_D   1.4426950408889634
#define PI_D      3.141592653589793
#define HALF_PI_D 1.5707963267948966
#define SQRT_2PI_D 2.5066282746310002

__device__ __forceinline__ float exp2_fast(float v) {
#if __has_builtin(__builtin_amdgcn_exp2f)
  return __builtin_amdgcn_exp2f(v);
#else
  return exp2f(v);
#endif
}

// ws layout (floats): [0,2048) = A (exp2 coefficient per (j,k)),
// [2048,4096) = W (weight per (j,k), includes duw_j and 2*pi*G*scale^2),
// [4096] = 1/scale^2, [4097] = bh_coef = G*10^m_bh/scale
__global__ __launch_bounds__(QN) void mge_setup(
    const float* __restrict__ surf, const float* __restrict__ sigma,
    const float* __restrict__ qobs, const float* __restrict__ M_to_L,
    const float* __restrict__ inc, const float* __restrict__ m_bh,
    float* __restrict__ ws)
{
  __shared__ double s_a[QN + 1], s_b[QN + 1];
  __shared__ double s_node[QN], s_wleg[QN];
  __shared__ double s_scal[4];                 // half, mid, mge_coef
  __shared__ double s_coef[KN], s_invsig2[KN], s_qintr2[KN];
  const int t = threadIdx.x;

  // cooperative: Legendre recurrence coefficients a_j=(2j-1)/j, b_j=(j-1)/j
  if (t < QN) { int j = t + 1; s_a[j] = (2.0 * j - 1.0) / j; s_b[j] = (double)(j - 1) / j; }
  __syncthreads();

  // Gauss-Legendre roots via Newton (fp64). Thread t<64 handles root pair (t, 127-t).
  if (t < QN / 2) {
    double z = cos(PI_D * (t + 0.75) / (QN + 0.5));
    double p1 = 0.0, pp = 0.0;
    for (int it = 0; it < 5; ++it) {
      p1 = 1.0; double p2 = 0.0;
      for (int j = 1; j <= QN; ++j) {
        double p3 = p2; p2 = p1;
        p1 = s_a[j] * z * p2 - s_b[j] * p3;
      }
      pp = QN * (z * p1 - p2) / (z * z - 1.0);
      if (it < 4) z -= p1 / pp;       // last pass just recomputes p1, pp at converged z
    }
    double w = 2.0 / ((1.0 - z * z) * pp * pp);
    s_node[t] = -z; s_node[QN - 1 - t] = z;     // ascending, matches leggauss
    s_wleg[t] = w;  s_wleg[QN - 1 - t] = w;
  }

  if (t == 0) {
    double cosi = cos((double)inc[0]), sini = sin((double)inc[0]);
    double ML = (double)M_to_L[0];
    // median of sigma: jnp.quantile(.,0.5), n=16 -> mean of sorted[7],[8]
    float ss[KN];
    for (int k = 0; k < KN; ++k) ss[k] = sigma[k];
    for (int i = 1; i < KN; ++i) {
      float v = ss[i]; int j = i - 1;
      while (j >= 0 && ss[j] > v) { ss[j + 1] = ss[j]; --j; }
      ss[j + 1] = v;
    }
    double scale = 0.5 * ((double)ss[KN/2 - 1] + (double)ss[KN/2]);
    double mds = 0.5 * ((double)ss[KN/2 - 1] / scale + (double)ss[KN/2] / scale); // = 1
    double mxs = (double)ss[KN - 1] / scale;
    double t_low  = asinh(log(1e-7 * mds) * 2.0 / PI_D);
    double t_high = asinh(log(1000.0 * mxs) * 2.0 / PI_D);
    s_scal[0] = 0.5 * (t_high - t_low);   // half
    s_scal[1] = 0.5 * (t_high + t_low);   // mid
    s_scal[2] = 2.0 * PI_D * G_CONST * scale * scale;  // mge coefficient (folded into W)
    for (int k = 0; k < KN; ++k) {
      double q = (double)qobs[k], sg = (double)sigma[k];
      double qi = sqrt(q * q - cosi * cosi) / sini;
      double md = (double)surf[k] * ML * q / (qi * sg * SQRT_2PI_D);
      double sgsc = sg / scale;
      s_coef[k] = qi * md;
      s_invsig2[k] = 1.0 / (sgsc * sgsc);
      s_qintr2[k] = qi * qi;
    }
    ws[2 * TERMS + 0] = (float)(1.0 / (scale * scale));
    ws[2 * TERMS + 1] = (float)(G_CONST * pow(10.0, (double)m_bh[0]) / scale);
  }
  __syncthreads();

  // each thread fills one quadrature row j = t of the A/W tables
  {
    double half = s_scal[0], mid = s_scal[1], mgec = s_scal[2];
    double tt = half * s_node[t] + mid;
    double sh = sinh(tt), ch = cosh(tt);
    double u  = exp(HALF_PI_D * sh);
    double duw = HALF_PI_D * ch * u * (half * s_wleg[t]);
    double op = 1.0 + u;
    double nh_over = -0.5 / op;
    double inv_op2 = 1.0 / (op * op);
    for (int k = 0; k < KN; ++k) {
      ws[t * KN + k]         = (float)(nh_over * s_invsig2[k] * LOG2E_D);
      ws[TERMS + t * KN + k] = (float)(mgec * duw * s_coef[k] * inv_op2 / sqrt(s_qintr2[k] + u));
    }
  }
}

__global__ __launch_bounds__(MBLK) void mge_main(
    const float* __restrict__ x, const float* __restrict__ y,
    const float* __restrict__ z, const float* __restrict__ ws,
    float* __restrict__ out, int n)
{
  __shared__ float sA[TERMS], sW[TERMS];
  const int t = threadIdx.x;
  for (int i = t; i < TERMS / 4; i += MBLK) {
    ((float4*)sA)[i] = ((const float4*)ws)[i];
    ((float4*)sW)[i] = ((const float4*)(ws + TERMS))[i];
  }
  const float inv_scale2 = ws[2 * TERMS];
  const float bh_coef    = ws[2 * TERMS + 1];
  __syncthreads();

  const int base = blockIdx.x * (MBLK * PPT) + t;
  float r2[PPT], acc[PPT];
#pragma unroll
  for (int i = 0; i < PPT; ++i) {
    int p = base + i * MBLK;
    float xx = 0.f, yy = 0.f, zz = 0.f;
    if (p < n) { xx = x[p]; yy = y[p]; zz = z[p]; }
    r2[i] = (xx * xx + yy * yy + zz * zz) * inv_scale2;
    acc[i] = 0.f;
  }

  const float4* A4 = (const float4*)sA;
  const float4* W4 = (const float4*)sW;
  for (int q = 0; q < TERMS / 4; ++q) {
    float4 a = A4[q], w = W4[q];
#pragma unroll
    for (int i = 0; i < PPT; ++i) {
      float r = r2[i];
      acc[i] += w.x * exp2_fast(a.x * r);
      acc[i] += w.y * exp2_fast(a.y * r);
      acc[i] += w.z * exp2_fast(a.z * r);
      acc[i] += w.w * exp2_fast(a.w * r);
    }
  }

#pragma unroll
  for (int i = 0; i < PPT; ++i) {
    int p = base + i * MBLK;
    if (p < n) {
      float r = r2[i];
      float rs = rsqrtf(r);                         // r^-1.5 = rs^3
      float vc2 = acc[i] + bh_coef * (rs * rs * rs);
      out[p] = sqrtf(r * vc2);
    }
  }
}

extern "C" void kernel_launch(void* const* d_in, const int* in_sizes, int n_in,
                              void* d_out, int out_size, void* d_ws, size_t ws_size,
                              hipStream_t stream) {
  const float* x      = (const float*)d_in[0];
  const float* y      = (const float*)d_in[1];
  const float* z      = (const float*)d_in[2];
  const float* surf   = (const float*)d_in[3];
  const float* sigma  = (const float*)d_in[4];
  const float* qobs   = (const float*)d_in[5];
  const float* M_to_L = (const float*)d_in[6];
  const float* inc    = (const float*)d_in[7];
  const float* m_bh   = (const float*)d_in[8];
  // d_in[9] = quad_points (int, always 128) — compiled in as QN

  float* ws  = (float*)d_ws;
  float* out = (float*)d_out;
  const int n = in_sizes[0];

  hipLaunchKernelGGL(mge_setup, dim3(1), dim3(QN), 0, stream,
                     surf, sigma, qobs, M_to_L, inc, m_bh, ws);
  const int per_block = MBLK * PPT;
  const int grid = (n + per_block - 1) / per_block;
  hipLaunchKernelGGL(mge_main, dim3(grid), dim3(MBLK), 0, stream,
                     x, y, z, ws, out, n);
}

// Round 2
// 114.064 us; speedup vs baseline: 2.9938x; 2.9938x over previous
//
#include <hip/hip_runtime.h>

#define QN 128
#define KN 16
#define TERMS (QN*KN)      // 2048
#define MBLK 256

#define TBL 4096
#define TMIN_F (-34.0f)
#define TMAX_F (16.0f)
#define DT_F   ((TMAX_F - TMIN_F) / (float)(TBL - 1))
#define INV_DT_F ((float)(TBL - 1) / (TMAX_F - TMIN_F))
#define TBL_OFF 4352       // float offset of table in ws (A:0..2048, W:2048..4096, scalars 4096..)

#define G_CONST   0.004301
#define LOG2E_D   1.4426950408889634
#define PI_D      3.141592653589793
#define HALF_PI_D 1.5707963267948966
#define SQRT_2PI_D 2.5066282746310002

__device__ __forceinline__ float exp2_fast(float v) {
#if __has_builtin(__builtin_amdgcn_exp2f)
  return __builtin_amdgcn_exp2f(v);
#else
  return exp2f(v);
#endif
}

// ws layout (floats): [0,2048) = A (exp2 coefficient per (j,k)),
// [2048,4096) = W (weight per (j,k), includes duw_j and 2*pi*G*scale^2),
// [4096] = 1/scale^2, [4097] = bh_coef = G*10^m_bh/scale
// [TBL_OFF, TBL_OFF+TBL) = F(R2) lookup table over t=log2(R2)
__global__ __launch_bounds__(QN) void mge_setup(
    const float* __restrict__ surf, const float* __restrict__ sigma,
    const float* __restrict__ qobs, const float* __restrict__ M_to_L,
    const float* __restrict__ inc, const float* __restrict__ m_bh,
    float* __restrict__ ws)
{
  __shared__ double s_a[QN + 1], s_b[QN + 1];
  __shared__ double s_node[QN], s_wleg[QN];
  __shared__ double s_scal[4];                 // half, mid, mge_coef
  __shared__ double s_coef[KN], s_invsig2[KN], s_qintr2[KN];
  const int t = threadIdx.x;

  // cooperative: Legendre recurrence coefficients a_j=(2j-1)/j, b_j=(j-1)/j
  if (t < QN) { int j = t + 1; s_a[j] = (2.0 * j - 1.0) / j; s_b[j] = (double)(j - 1) / j; }
  __syncthreads();

  // Gauss-Legendre roots via Newton (fp64). Thread t<64 handles root pair (t, 127-t).
  if (t < QN / 2) {
    double z = cos(PI_D * (t + 0.75) / (QN + 0.5));
    double p1 = 0.0, pp = 0.0;
    for (int it = 0; it < 5; ++it) {
      p1 = 1.0; double p2 = 0.0;
      for (int j = 1; j <= QN; ++j) {
        double p3 = p2; p2 = p1;
        p1 = s_a[j] * z * p2 - s_b[j] * p3;
      }
      pp = QN * (z * p1 - p2) / (z * z - 1.0);
      if (it < 4) z -= p1 / pp;       // last pass just recomputes p1, pp at converged z
    }
    double w = 2.0 / ((1.0 - z * z) * pp * pp);
    s_node[t] = -z; s_node[QN - 1 - t] = z;     // ascending, matches leggauss
    s_wleg[t] = w;  s_wleg[QN - 1 - t] = w;
  }

  if (t == 0) {
    double cosi = cos((double)inc[0]), sini = sin((double)inc[0]);
    double ML = (double)M_to_L[0];
    // median of sigma: jnp.quantile(.,0.5), n=16 -> mean of sorted[7],[8]
    float ss[KN];
    for (int k = 0; k < KN; ++k) ss[k] = sigma[k];
    for (int i = 1; i < KN; ++i) {
      float v = ss[i]; int j = i - 1;
      while (j >= 0 && ss[j] > v) { ss[j + 1] = ss[j]; --j; }
      ss[j + 1] = v;
    }
    double scale = 0.5 * ((double)ss[KN/2 - 1] + (double)ss[KN/2]);
    double mds = 0.5 * ((double)ss[KN/2 - 1] / scale + (double)ss[KN/2] / scale); // = 1
    double mxs = (double)ss[KN - 1] / scale;
    double t_low  = asinh(log(1e-7 * mds) * 2.0 / PI_D);
    double t_high = asinh(log(1000.0 * mxs) * 2.0 / PI_D);
    s_scal[0] = 0.5 * (t_high - t_low);   // half
    s_scal[1] = 0.5 * (t_high + t_low);   // mid
    s_scal[2] = 2.0 * PI_D * G_CONST * scale * scale;  // mge coefficient (folded into W)
    for (int k = 0; k < KN; ++k) {
      double q = (double)qobs[k], sg = (double)sigma[k];
      double qi = sqrt(q * q - cosi * cosi) / sini;
      double md = (double)surf[k] * ML * q / (qi * sg * SQRT_2PI_D);
      double sgsc = sg / scale;
      s_coef[k] = qi * md;
      s_invsig2[k] = 1.0 / (sgsc * sgsc);
      s_qintr2[k] = qi * qi;
    }
    ws[2 * TERMS + 0] = (float)(1.0 / (scale * scale));
    ws[2 * TERMS + 1] = (float)(G_CONST * pow(10.0, (double)m_bh[0]) / scale);
  }
  __syncthreads();

  // each thread fills one quadrature row j = t of the A/W tables
  {
    double half = s_scal[0], mid = s_scal[1], mgec = s_scal[2];
    double tt = half * s_node[t] + mid;
    double sh = sinh(tt), ch = cosh(tt);
    double u  = exp(HALF_PI_D * sh);
    double duw = HALF_PI_D * ch * u * (half * s_wleg[t]);
    double op = 1.0 + u;
    double nh_over = -0.5 / op;
    double inv_op2 = 1.0 / (op * op);
    for (int k = 0; k < KN; ++k) {
      ws[t * KN + k]         = (float)(nh_over * s_invsig2[k] * LOG2E_D);
      ws[TERMS + t * KN + k] = (float)(mgec * duw * s_coef[k] * inv_op2 / sqrt(s_qintr2[k] + u));
    }
  }
}

// one wave per table entry: F(R2_i) = sum_jk W * exp2(A * R2_i)
__global__ __launch_bounds__(256) void mge_table(
    const float* __restrict__ ws, float* __restrict__ tbl)
{
  const int lane = threadIdx.x & 63;
  const int wave = threadIdx.x >> 6;
  const int entry = blockIdx.x * 4 + wave;
  const float r2 = exp2_fast(TMIN_F + entry * DT_F);
  const float* __restrict__ A = ws;
  const float* __restrict__ W = ws + TERMS;
  float acc = 0.f;
  for (int q = lane; q < TERMS; q += 64)
    acc += W[q] * exp2_fast(A[q] * r2);
#pragma unroll
  for (int off = 32; off; off >>= 1) acc += __shfl_down(acc, off);
  if (lane == 0) tbl[entry] = acc;
}

__global__ __launch_bounds__(MBLK) void mge_main(
    const float* __restrict__ x, const float* __restrict__ y,
    const float* __restrict__ z, const float* __restrict__ ws,
    float* __restrict__ out, int n)
{
  __shared__ float sT[TBL];
  const int t = threadIdx.x;
  const float* __restrict__ tbl = ws + TBL_OFF;
  for (int i = t; i < TBL / 4; i += MBLK)
    ((float4*)sT)[i] = ((const float4*)tbl)[i];
  const float inv_scale2 = ws[2 * TERMS];
  const float bh_coef    = ws[2 * TERMS + 1];
  __syncthreads();

  const int g = blockIdx.x * MBLK + t;      // float4 group index
  const int base = 4 * g;
  if (base + 3 < n) {
    float4 xv = ((const float4*)x)[g];
    float4 yv = ((const float4*)y)[g];
    float4 zv = ((const float4*)z)[g];
    float r2[4] = {
      (xv.x*xv.x + yv.x*yv.x + zv.x*zv.x) * inv_scale2,
      (xv.y*xv.y + yv.y*yv.y + zv.y*zv.y) * inv_scale2,
      (xv.z*xv.z + yv.z*yv.z + zv.z*zv.z) * inv_scale2,
      (xv.w*xv.w + yv.w*yv.w + zv.w*zv.w) * inv_scale2 };
    float4 ov;
    float* o = &ov.x;
#pragma unroll
    for (int i = 0; i < 4; ++i) {
      float r = r2[i];
      float idxf = (__log2f(r) - TMIN_F) * INV_DT_F;
      idxf = fminf(fmaxf(idxf, 0.0f), (float)(TBL - 1) - 0.001f);
      int ii = (int)idxf;
      float frac = idxf - (float)ii;
      float f0 = sT[ii], f1 = sT[ii + 1];
      float F = f0 + frac * (f1 - f0);
      float rs = rsqrtf(r);
      float vc2 = F + bh_coef * (rs * rs * rs);
      o[i] = sqrtf(r * vc2);
    }
    ((float4*)out)[g] = ov;
  } else {
    for (int p = base; p < n; ++p) {
      float xx = x[p], yy = y[p], zz = z[p];
      float r = (xx*xx + yy*yy + zz*zz) * inv_scale2;
      float idxf = (__log2f(r) - TMIN_F) * INV_DT_F;
      idxf = fminf(fmaxf(idxf, 0.0f), (float)(TBL - 1) - 0.001f);
      int ii = (int)idxf;
      float frac = idxf - (float)ii;
      float f0 = sT[ii], f1 = sT[ii + 1];
      float F = f0 + frac * (f1 - f0);
      float rs = rsqrtf(r);
      float vc2 = F + bh_coef * (rs * rs * rs);
      out[p] = sqrtf(r * vc2);
    }
  }
}

extern "C" void kernel_launch(void* const* d_in, const int* in_sizes, int n_in,
                              void* d_out, int out_size, void* d_ws, size_t ws_size,
                              hipStream_t stream) {
  const float* x      = (const float*)d_in[0];
  const float* y      = (const float*)d_in[1];
  const float* z      = (const float*)d_in[2];
  const float* surf   = (const float*)d_in[3];
  const float* sigma  = (const float*)d_in[4];
  const float* qobs   = (const float*)d_in[5];
  const float* M_to_L = (const float*)d_in[6];
  const float* inc    = (const float*)d_in[7];
  const float* m_bh   = (const float*)d_in[8];
  // d_in[9] = quad_points (int, always 128) — compiled in as QN

  float* ws  = (float*)d_ws;
  float* out = (float*)d_out;
  const int n = in_sizes[0];

  hipLaunchKernelGGL(mge_setup, dim3(1), dim3(QN), 0, stream,
                     surf, sigma, qobs, M_to_L, inc, m_bh, ws);
  hipLaunchKernelGGL(mge_table, dim3(TBL / 4), dim3(256), 0, stream,
                     ws, ws + TBL_OFF);
  const int grid = (n / 4 + MBLK - 1) / MBLK;
  hipLaunchKernelGGL(mge_main, dim3(grid), dim3(MBLK), 0, stream,
                     x, y, z, ws, out, n);
}

// Round 3
// 102.012 us; speedup vs baseline: 3.3475x; 1.1181x over previous
//
#include <hip/hip_runtime.h>

#define QN 128
#define KN 16
#define TERMS (QN*KN)      // 2048
#define MBLK 256

#define TBL 2048
#define BBLK 128           // build blocks
#define EPB  (TBL/BBLK)    // 16 entries per build block
#define TPE  (256/EPB)     // 16 threads per entry

#define TMIN_F (-34.0f)
#define TMAX_F (16.0f)
#define DT_F   ((TMAX_F - TMIN_F) / (float)(TBL - 1))
#define INV_DT_F ((float)(TBL - 1) / (TMAX_F - TMIN_F))
#define TBL_OFF 16         // float offset of table in ws; ws[0]=inv_scale2, ws[1]=bh_coef

#define G_CONST   0.004301
#define LOG2E_D   1.4426950408889634
#define PI_D      3.141592653589793
#define HALF_PI_D 1.5707963267948966
#define SQRT_2PI_D 2.5066282746310002

__device__ __forceinline__ float exp2_fast(float v) {
#if __has_builtin(__builtin_amdgcn_exp2f)
  return __builtin_amdgcn_exp2f(v);
#else
  return exp2f(v);
#endif
}

// One kernel builds everything. Every block redundantly does the (cheap,
// parallel) fp64 setup, then computes its own 16 entries of the F(R2) table.
// No atomics, no global A/W round-trip, no cross-block dependencies.
__global__ __launch_bounds__(256) void mge_build(
    const float* __restrict__ surf, const float* __restrict__ sigma,
    const float* __restrict__ qobs, const float* __restrict__ M_to_L,
    const float* __restrict__ inc, const float* __restrict__ m_bh,
    float* __restrict__ ws)
{
  __shared__ double s_a[QN + 1], s_b[QN + 1];
  __shared__ double s_node[QN], s_wleg[QN];
  __shared__ double s_scal[3];                 // half, mid, mge_coef
  __shared__ double s_coef[KN], s_invsig2[KN], s_qintr2[KN];
  __shared__ float sA[TERMS], sW[TERMS];
  const int t = threadIdx.x;

  // Legendre recurrence coefficients a_j=(2j-1)/j, b_j=(j-1)/j
  if (t < QN) { int j = t + 1; s_a[j] = (2.0 * j - 1.0) / j; s_b[j] = (double)(j - 1) / j; }
  __syncthreads();

  // wave 0: Gauss-Legendre roots via Newton (fp64), lane t handles pair (t, 127-t)
  if (t < QN / 2) {
    double z = cos(PI_D * (t + 0.75) / (QN + 0.5));
    double p1 = 0.0, pp = 0.0;
    for (int it = 0; it < 5; ++it) {
      p1 = 1.0; double p2 = 0.0;
      for (int j = 1; j <= QN; ++j) {
        double p3 = p2; p2 = p1;
        p1 = s_a[j] * z * p2 - s_b[j] * p3;
      }
      pp = QN * (z * p1 - p2) / (z * z - 1.0);
      if (it < 4) z -= p1 / pp;       // last pass recomputes p1, pp at converged z
    }
    double w = 2.0 / ((1.0 - z * z) * pp * pp);
    s_node[t] = -z; s_node[QN - 1 - t] = z;     // ascending, matches leggauss
    s_wleg[t] = w;  s_wleg[QN - 1 - t] = w;
  }

  // wave 3 (runs concurrently with wave 0's Newton): scalar prep
  if (t == 192) {
    double cosi = cos((double)inc[0]), sini = sin((double)inc[0]);
    double ML = (double)M_to_L[0];
    // median of sigma: jnp.quantile(.,0.5), n=16 -> mean of sorted[7],[8]
    float ss[KN];
    for (int k = 0; k < KN; ++k) ss[k] = sigma[k];
    for (int i = 1; i < KN; ++i) {
      float v = ss[i]; int j = i - 1;
      while (j >= 0 && ss[j] > v) { ss[j + 1] = ss[j]; --j; }
      ss[j + 1] = v;
    }
    double scale = 0.5 * ((double)ss[KN/2 - 1] + (double)ss[KN/2]);
    double mds = 0.5 * ((double)ss[KN/2 - 1] / scale + (double)ss[KN/2] / scale); // = 1
    double mxs = (double)ss[KN - 1] / scale;
    double t_low  = asinh(log(1e-7 * mds) * 2.0 / PI_D);
    double t_high = asinh(log(1000.0 * mxs) * 2.0 / PI_D);
    s_scal[0] = 0.5 * (t_high - t_low);   // half
    s_scal[1] = 0.5 * (t_high + t_low);   // mid
    s_scal[2] = 2.0 * PI_D * G_CONST * scale * scale;
    for (int k = 0; k < KN; ++k) {
      double q = (double)qobs[k], sg = (double)sigma[k];
      double qi = sqrt(q * q - cosi * cosi) / sini;
      double md = (double)surf[k] * ML * q / (qi * sg * SQRT_2PI_D);
      double sgsc = sg / scale;
      s_coef[k] = qi * md;
      s_invsig2[k] = 1.0 / (sgsc * sgsc);
      s_qintr2[k] = qi * qi;
    }
    if (blockIdx.x == 0) {
      ws[0] = (float)(1.0 / (scale * scale));
      ws[1] = (float)(G_CONST * pow(10.0, (double)m_bh[0]) / scale);
    }
  }
  __syncthreads();

  // phase B: thread j<128 fills quadrature row j of the LDS A/W tables
  if (t < QN) {
    double half = s_scal[0], mid = s_scal[1], mgec = s_scal[2];
    double tt = half * s_node[t] + mid;
    double sh = sinh(tt), ch = cosh(tt);
    double u  = exp(HALF_PI_D * sh);
    double duw = HALF_PI_D * ch * u * (half * s_wleg[t]);
    double op = 1.0 + u;
    double nh_over = -0.5 / op;
    double inv_op2 = 1.0 / (op * op);
    for (int k = 0; k < KN; ++k) {
      sA[t * KN + k] = (float)(nh_over * s_invsig2[k] * LOG2E_D);
      sW[t * KN + k] = (float)(mgec * duw * s_coef[k] * inv_op2 / sqrt(s_qintr2[k] + u));
    }
  }
  __syncthreads();

  // phase C: 16 threads per entry, strided LDS reads (broadcast, conflict-free)
  const int e   = t / TPE;
  const int sub = t % TPE;
  const int entry = blockIdx.x * EPB + e;
  const float r2 = exp2_fast(TMIN_F + entry * DT_F);
  float acc = 0.f;
  for (int q = sub; q < TERMS; q += TPE)
    acc += sW[q] * exp2_fast(sA[q] * r2);
#pragma unroll
  for (int off = TPE / 2; off; off >>= 1) acc += __shfl_down(acc, off);
  if (sub == 0) ws[TBL_OFF + entry] = acc;
}

__global__ __launch_bounds__(MBLK) void mge_main(
    const float* __restrict__ x, const float* __restrict__ y,
    const float* __restrict__ z, const float* __restrict__ ws,
    float* __restrict__ out, int n)
{
  __shared__ float sT[TBL];
  const int t = threadIdx.x;
  const float* __restrict__ tbl = ws + TBL_OFF;
  for (int i = t; i < TBL / 4; i += MBLK)
    ((float4*)sT)[i] = ((const float4*)tbl)[i];
  const float inv_scale2 = ws[0];
  const float bh_coef    = ws[1];
  __syncthreads();

  const int g = blockIdx.x * MBLK + t;      // float4 group index
  const int base = 4 * g;
  if (base + 3 < n) {
    float4 xv = ((const float4*)x)[g];
    float4 yv = ((const float4*)y)[g];
    float4 zv = ((const float4*)z)[g];
    float r2[4] = {
      (xv.x*xv.x + yv.x*yv.x + zv.x*zv.x) * inv_scale2,
      (xv.y*xv.y + yv.y*yv.y + zv.y*zv.y) * inv_scale2,
      (xv.z*xv.z + yv.z*yv.z + zv.z*zv.z) * inv_scale2,
      (xv.w*xv.w + yv.w*yv.w + zv.w*zv.w) * inv_scale2 };
    float4 ov;
    float* o = &ov.x;
#pragma unroll
    for (int i = 0; i < 4; ++i) {
      float r = r2[i];
      float idxf = (__log2f(r) - TMIN_F) * INV_DT_F;
      idxf = fminf(fmaxf(idxf, 0.0f), (float)(TBL - 1) - 0.001f);
      int ii = (int)idxf;
      float frac = idxf - (float)ii;
      float f0 = sT[ii], f1 = sT[ii + 1];
      float F = f0 + frac * (f1 - f0);
      float rs = rsqrtf(r);
      float vc2 = F + bh_coef * (rs * rs * rs);
      o[i] = sqrtf(r * vc2);
    }
    ((float4*)out)[g] = ov;
  } else {
    for (int p = base; p < n; ++p) {
      float xx = x[p], yy = y[p], zz = z[p];
      float r = (xx*xx + yy*yy + zz*zz) * inv_scale2;
      float idxf = (__log2f(r) - TMIN_F) * INV_DT_F;
      idxf = fminf(fmaxf(idxf, 0.0f), (float)(TBL - 1) - 0.001f);
      int ii = (int)idxf;
      float frac = idxf - (float)ii;
      float f0 = sT[ii], f1 = sT[ii + 1];
      float F = f0 + frac * (f1 - f0);
      float rs = rsqrtf(r);
      float vc2 = F + bh_coef * (rs * rs * rs);
      out[p] = sqrtf(r * vc2);
    }
  }
}

extern "C" void kernel_launch(void* const* d_in, const int* in_sizes, int n_in,
                              void* d_out, int out_size, void* d_ws, size_t ws_size,
                              hipStream_t stream) {
  const float* x      = (const float*)d_in[0];
  const float* y      = (const float*)d_in[1];
  const float* z      = (const float*)d_in[2];
  const float* surf   = (const float*)d_in[3];
  const float* sigma  = (const float*)d_in[4];
  const float* qobs   = (const float*)d_in[5];
  const float* M_to_L = (const float*)d_in[6];
  const float* inc    = (const float*)d_in[7];
  const float* m_bh   = (const float*)d_in[8];
  // d_in[9] = quad_points (int, always 128) — compiled in as QN

  float* ws  = (float*)d_ws;
  float* out = (float*)d_out;
  const int n = in_sizes[0];

  hipLaunchKernelGGL(mge_build, dim3(BBLK), dim3(256), 0, stream,
                     surf, sigma, qobs, M_to_L, inc, m_bh, ws);
  const int grid = (n / 4 + MBLK - 1) / MBLK;
  hipLaunchKernelGGL(mge_main, dim3(grid), dim3(MBLK), 0, stream,
                     x, y, z, ws, out, n);
}